// Round 12
// baseline (773.217 us; speedup 1.0000x reference)
//
#include <hip/hip_runtime.h>
#include <math.h>

// ---- geometry constants (match reference) ----
#define NA   24
#define NU   128
#define NV   64
#define NW   128   // volume W (x)
#define NH   128   // volume H (y)
#define ND   64    // volume D (z)
#define NS   128   // samples per ray
#define F_STEP 1.5625f            // 2*HS/S = 200/128
#define F_DL  (200.0f / 127.0f)   // linspace(156,356,128) spacing
#define F_L0  156.0f
#define INV_DL (127.0f / 200.0f)

#define NRAYS (NA * NV * NU)      // 196608
#define VOX   (NW * NH * ND)      // 1048576
#define NSEG  4

typedef float v2f __attribute__((ext_vector_type(2)));

// cos/sin(k*15 deg)
__device__ __constant__ float CSA[NA] = {
    1.0f,  0.96592582628906829f,  0.86602540378443865f,  0.70710678118654752f,
    0.5f,  0.25881904510252076f,  0.0f,                 -0.25881904510252076f,
   -0.5f, -0.70710678118654752f, -0.86602540378443865f, -0.96592582628906829f,
   -1.0f, -0.96592582628906829f, -0.86602540378443865f, -0.70710678118654752f,
   -0.5f, -0.25881904510252076f,  0.0f,                  0.25881904510252076f,
    0.5f,  0.70710678118654752f,  0.86602540378443865f,  0.96592582628906829f
};
__device__ __constant__ float SNA[NA] = {
    0.0f,  0.25881904510252076f,  0.5f,                  0.70710678118654752f,
    0.86602540378443865f,  0.96592582628906829f,  1.0f,  0.96592582628906829f,
    0.86602540378443865f,  0.70710678118654752f,  0.5f,  0.25881904510252076f,
    0.0f, -0.25881904510252076f, -0.5f,                 -0.70710678118654752f,
   -0.86602540378443865f, -0.96592582628906829f, -1.0f, -0.96592582628906829f,
   -0.86602540378443865f, -0.70710678118654752f, -0.5f, -0.25881904510252076f
};

// Per-ray geometry for FP.
__device__ __forceinline__ void ray_setup(int a, int v, int u,
                                          float& sx, float& sy,
                                          float& dx, float& dy, float& dz) {
    float ang = (float)((double)a * (15.0 * M_PI / 180.0));
    float c = cosf(ang), s = sinf(ang);
    float uu = (float)u - 63.5f;
    float vv = (float)v - 31.5f;
    float ux = 512.0f * c - uu * s;
    float uy = 512.0f * s + uu * c;
    float uz = vv;
    float invn = 1.0f / sqrtf(ux * ux + uy * uy + uz * uz);
    dx = ux * invn; dy = uy * invn; dz = uz * invn;
    sx = -256.0f * c; sy = -256.0f * s;
}

// ---------------- forward projection, 4 ell-segments ----------------
__global__ __launch_bounds__(256) void fp_seg_kernel(const float* __restrict__ vol,
                                                     float* __restrict__ part) {
    int r = blockIdx.x * blockDim.x + threadIdx.x;
    int seg = blockIdx.y;
    int u = r & (NU - 1);
    int v = (r >> 7) & (NV - 1);
    int a = r >> 13;

    float sx, sy, dx, dy, dz;
    ray_setup(a, v, u, sx, sy, dx, dy, dz);

    float rx = 1.0f / dx, ry = 1.0f / dy, rz = 1.0f / dz;
    float ex0 = (-64.55f - sx) * rx, ex1 = (64.55f - sx) * rx;
    float ey0 = (-64.55f - sy) * ry, ey1 = (64.55f - sy) * ry;
    float ez0 = (-32.55f) * rz,      ez1 = (32.55f) * rz;
    float llo = fmaxf(fmaxf(fminf(ex0, ex1), fminf(ey0, ey1)), fminf(ez0, ez1));
    float lhi = fminf(fminf(fmaxf(ex0, ex1), fmaxf(ey0, ey1)), fmaxf(ez0, ez1));
    int i_lo = max(seg * 32,      (int)ceilf((llo - F_L0) * INV_DL));
    int i_hi = min(seg * 32 + 31, (int)floorf((lhi - F_L0) * INV_DL));

    float acc = 0.0f;
    for (int i = i_lo; i <= i_hi; ++i) {
        float ell = F_L0 + F_DL * (float)i;
        float cx = sx + ell * dx + 63.5f;
        float cy = sy + ell * dy + 63.5f;
        float cz =      ell * dz + 31.5f;
        float fx = floorf(cx), fy = floorf(cy), fz = floorf(cz);
        int ix = (int)fx, iy = (int)fy, iz = (int)fz;
        float wx1 = cx - fx, wy1 = cy - fy, wz1 = cz - fz;
        float wx0 = 1.0f - wx1, wy0 = 1.0f - wy1, wz0 = 1.0f - wz1;
        bool bx0 = (unsigned)ix < NW,      bx1 = (unsigned)(ix + 1) < NW;
        bool by0 = (unsigned)iy < NH,      by1 = (unsigned)(iy + 1) < NH;
        bool bz0 = (unsigned)iz < ND,      bz1 = (unsigned)(iz + 1) < ND;
        long base = ((long)iz * NH + iy) * NW + ix;
        float v000 = (bz0 && by0 && bx0) ? vol[base]                 : 0.0f;
        float v001 = (bz0 && by0 && bx1) ? vol[base + 1]             : 0.0f;
        float v010 = (bz0 && by1 && bx0) ? vol[base + NW]            : 0.0f;
        float v011 = (bz0 && by1 && bx1) ? vol[base + NW + 1]        : 0.0f;
        float v100 = (bz1 && by0 && bx0) ? vol[base + NH * NW]       : 0.0f;
        float v101 = (bz1 && by0 && bx1) ? vol[base + NH * NW + 1]   : 0.0f;
        float v110 = (bz1 && by1 && bx0) ? vol[base + NH * NW + NW]  : 0.0f;
        float v111 = (bz1 && by1 && bx1) ? vol[base + NH * NW + NW + 1] : 0.0f;
        acc += wz0 * (wy0 * (wx0 * v000 + wx1 * v001) +
                      wy1 * (wx0 * v010 + wx1 * v011)) +
               wz1 * (wy0 * (wx0 * v100 + wx1 * v101) +
                      wy1 * (wx0 * v110 + wx1 * v111));
    }
    part[seg * NRAYS + r] = acc;
}

// ------- residual + cw + Ram-Lak; writes TRANSPOSED resT[a][u][v] -------
__global__ __launch_bounds__(NU) void ramp_kernel(const float* __restrict__ part,
                                                  const float* __restrict__ p,
                                                  float* __restrict__ resT) {
    __shared__ float row[NU];
    int rowid = blockIdx.x;          // a*NV + v
    int u = threadIdx.x;
    int e = rowid * NU + u;
    int a = rowid >> 6;
    int v = rowid & (NV - 1);
    float sino = (part[e] + part[NRAYS + e] + part[2 * NRAYS + e] + part[3 * NRAYS + e]) * F_STEP;
    double du = (double)u - 64.0;
    double dv = (double)v - 32.0;
    float cw = (float)(512.0 / sqrt(262144.0 + dv * dv + du * du));
    row[u] = (sino - p[e]) * cw;
    __syncthreads();
    float acc = 0.125f * row[u];
#pragma unroll
    for (int d = 1; d <= 63; d += 2) {
        float f = (float)(-0.5 / (M_PI * M_PI * (double)(d * d)));
        float lo = (u - d >= 0) ? row[u - d] : 0.0f;
        float hi = (u + d < NU) ? row[u + d] : 0.0f;
        acc += f * (lo + hi);
    }
    resT[(a << 13) + (u << 6) + v] = acc;   // [a][u][v]
}

// ---------------- back projection: quad-angle interleaved gather ----------------
// Wave = one xy-column, lane = v. Angles (j, j+6, j+12, j+18) share trig via 90deg
// symmetry: P = x0 c + y0 s, Q = y0 c - x0 s give rho = 256+{P,Q,-P,-Q},
// yp = {Q,-P,-Q,P}. Four independent chains/wave + one-ahead prefetch cover the
// load->use latency that pinned R8-R11 at ~430-480us. Out-of-window iterations
// self-zero geometrically; prefetch may read 1 column past the window (stays
// inside ws: part[] follows resT).

#define SETUP_A(S, RHO, YP, CC, SS, AIDX)                                        \
    const float c##S = (CC), sn##S = (SS);                                       \
    const float rho##S = (RHO), yp##S = (YP);                                    \
    const float tvlo##S = (rho##S - ab1) * (1.0f / 512.0f);                      \
    const float rl##S = __builtin_amdgcn_rcpf(rho##S - ab1);                     \
    const float rh##S = __builtin_amdgcn_rcpf(rho##S + ab1);                     \
    const float A##S = yp##S - ab1, B##S = yp##S + ab1;                          \
    const float um##S = 512.0f * A##S * ((A##S >= 0.0f) ? rh##S : rl##S);        \
    const float uM##S = 512.0f * B##S * ((B##S >= 0.0f) ? rl##S : rh##S);        \
    const int u_lo##S = max(0,   (int)ceilf(um##S + 63.49f));                    \
    const int u_hi##S = min(127, (int)floorf(uM##S + 63.51f));                   \
    const int len##S = max(0, u_hi##S - u_lo##S + 1);                            \
    const float Zmin##S = fmaf(vvf, (vvf >= 0.0f) ? (tvlo##S - 1.0e-3f)          \
                                                  : (tvlo##S + 7.2e-3f), 31.5f); \
    const float izbf##S = floorf(Zmin##S);                                       \
    const int   izb##S  = (int)izbf##S;                                          \
    const v2f b0##S = {izbf##S, izbf##S};                                        \
    const float tDL##S = tvlo##S * INV_DL;                                       \
    const v2f mVx##S = {-(x0 + 256.0f * c##S), -(x0 + 256.0f * c##S)};           \
    const v2f mVy##S = {-(y0 + 256.0f * sn##S), -(y0 + 256.0f * sn##S)};         \
    const int aoff##S = (AIDX) << 13;

#define BP_BODY4(S, RV, UU) do {                                                 \
    const float pu = fmaf(-(UU), sn##S, 512.0f * c##S);                          \
    const float qu = fmaf((UU), c##S, 512.0f * sn##S);                           \
    const float arg  = fmaf((UU), (UU), s2);                                     \
    const float invn = __builtin_amdgcn_rsqf(arg);                               \
    const float nn   = arg * invn;                                               \
    const float i0f  = ceilf(fmaf(tDL##S, nn, cK));                              \
    const float ell0 = fmaf(i0f, F_DL, F_L0);                                    \
    v2f tp; tp.x = ell0 * invn; tp.y = fmaf(F_DL, invn, tp.x);                   \
    const v2f pu2 = {pu, pu}, qu2 = {qu, qu};                                    \
    v2f wx = __builtin_elementwise_max(                                          \
        one2 - __builtin_elementwise_abs(__builtin_elementwise_fma(tp, pu2, mVx##S)), zero2); \
    v2f wy = __builtin_elementwise_max(                                          \
        one2 - __builtin_elementwise_abs(__builtin_elementwise_fma(tp, qu2, mVy##S)), zero2); \
    v2f val = wx * wy * (v2f){(RV), (RV)};                                       \
    const v2f fz2 = __builtin_elementwise_fma(tp, vv2, h31);                     \
    const v2f g = fz2 - b0##S;                                                   \
    AC0##S = __builtin_elementwise_fma(__builtin_elementwise_max(                \
             one2 - __builtin_elementwise_abs(g), zero2), val, AC0##S);          \
    AC1##S = __builtin_elementwise_fma(__builtin_elementwise_max(                \
             one2 - __builtin_elementwise_abs(g - one2), zero2), val, AC1##S);   \
    AC2##S = __builtin_elementwise_fma(__builtin_elementwise_max(                \
             one2 - __builtin_elementwise_abs(g - two2), zero2), val, AC2##S);   \
    AC3##S = __builtin_elementwise_fma(__builtin_elementwise_max(                \
             one2 - __builtin_elementwise_abs(g - thr2), zero2), val, AC3##S);   \
} while (0)

__global__ __launch_bounds__(256, 4) void bp_gather10(const float* __restrict__ resT,
                                                      float* __restrict__ out) {
    __shared__ float s_acc[4 * 64];       // per-wave z-accumulator columns

    const int tid  = threadIdx.x;
    const int lane = tid & 63;            // = v
    const int wv   = tid >> 6;            // wave 0..3
    const int y    = blockIdx.x & 127;    // y-major
    const int xq   = blockIdx.x >> 7;     // 0..31
    const int xi   = xq * 4 + wv;         // 4 consecutive x per block

    const float x0 = (float)xi - 63.5f;
    const float y0 = (float)y  - 63.5f;
    const float vvf = (float)lane - 31.5f;
    const float s2  = fmaf(vvf, vvf, 262144.0f);
    const v2f vv2   = {vvf, vvf};
    const v2f one2  = {1.0f, 1.0f}, zero2 = {0.0f, 0.0f};
    const v2f two2  = {2.0f, 2.0f}, thr2  = {3.0f, 3.0f};
    const v2f h31   = {31.5f, 31.5f};
    const float cK  = -(F_L0 * INV_DL) - 1.0e-3f;

    s_acc[tid] = 0.0f;

    for (int j = 0; j < 6; ++j) {
        const float c  = CSA[j];
        const float sn = SNA[j];
        const float ab1 = fabsf(c) + fabsf(sn);
        const float P = fmaf(x0, c, y0 * sn);
        const float Q = fmaf(y0, c, -x0 * sn);

        SETUP_A(0, 256.0f + P,  Q,   c,   sn,  j);        // angle j
        SETUP_A(1, 256.0f + Q, -P,  -sn,  c,   j + 6);    // +90 deg
        SETUP_A(2, 256.0f - P, -Q,  -c,  -sn,  j + 12);   // +180
        SETUP_A(3, 256.0f - Q,  P,   sn, -c,   j + 18);   // +270

        const int trips = max(max(len0, len1), max(len2, len3));
        if (trips == 0) continue;
        const int us0 = max(0, min(u_lo0, 128 - trips));
        const int us1 = max(0, min(u_lo1, 128 - trips));
        const int us2 = max(0, min(u_lo2, 128 - trips));
        const int us3 = max(0, min(u_lo3, 128 - trips));

        v2f AC00 = zero2, AC10 = zero2, AC20 = zero2, AC30 = zero2;
        v2f AC01 = zero2, AC11 = zero2, AC21 = zero2, AC31 = zero2;
        v2f AC02 = zero2, AC12 = zero2, AC22 = zero2, AC32 = zero2;
        v2f AC03 = zero2, AC13 = zero2, AC23 = zero2, AC33 = zero2;

        const float* ru0 = resT + aoff0 + (us0 << 6) + lane;
        const float* ru1 = resT + aoff1 + (us1 << 6) + lane;
        const float* ru2 = resT + aoff2 + (us2 << 6) + lane;
        const float* ru3 = resT + aoff3 + (us3 << 6) + lane;
        float uu0 = (float)us0 - 63.5f;
        float uu1 = (float)us1 - 63.5f;
        float uu2 = (float)us2 - 63.5f;
        float uu3 = (float)us3 - 63.5f;

        float rv0 = ru0[0], rv1 = ru1[0], rv2 = ru2[0], rv3 = ru3[0];
#pragma unroll 1
        for (int k = 0; k < trips; ++k) {
            ru0 += 64; ru1 += 64; ru2 += 64; ru3 += 64;
            const float nv0 = ru0[0];      // one-ahead prefetch (may read 1 col
            const float nv1 = ru1[0];      //  past window; lands in ws, unused)
            const float nv2 = ru2[0];
            const float nv3 = ru3[0];
            BP_BODY4(0, rv0, uu0);
            BP_BODY4(1, rv1, uu1);
            BP_BODY4(2, rv2, uu2);
            BP_BODY4(3, rv3, uu3);
            rv0 = nv0; rv1 = nv1; rv2 = nv2; rv3 = nv3;
            uu0 += 1.0f; uu1 += 1.0f; uu2 += 1.0f; uu3 += 1.0f;
        }

        float* accw = s_acc + (wv << 6);
        atomicAdd(&accw[izb0],     AC00.x + AC00.y);
        atomicAdd(&accw[izb0 + 1], AC10.x + AC10.y);
        atomicAdd(&accw[izb0 + 2], AC20.x + AC20.y);
        atomicAdd(&accw[izb0 + 3], AC30.x + AC30.y);
        atomicAdd(&accw[izb1],     AC01.x + AC01.y);
        atomicAdd(&accw[izb1 + 1], AC11.x + AC11.y);
        atomicAdd(&accw[izb1 + 2], AC21.x + AC21.y);
        atomicAdd(&accw[izb1 + 3], AC31.x + AC31.y);
        atomicAdd(&accw[izb2],     AC02.x + AC02.y);
        atomicAdd(&accw[izb2 + 1], AC12.x + AC12.y);
        atomicAdd(&accw[izb2 + 2], AC22.x + AC22.y);
        atomicAdd(&accw[izb2 + 3], AC32.x + AC32.y);
        atomicAdd(&accw[izb3],     AC03.x + AC03.y);
        atomicAdd(&accw[izb3 + 1], AC13.x + AC13.y);
        atomicAdd(&accw[izb3 + 2], AC23.x + AC23.y);
        atomicAdd(&accw[izb3 + 3], AC33.x + AC33.y);
    }
    __syncthreads();

    // writeout: 4 consecutive x per 4 lanes -> 16B chunks
    const int z  = tid >> 2;
    const int w4 = tid & 3;
    out[(z << 14) + (y << 7) + xq * 4 + w4] = s_acc[(w4 << 6) + z] * F_STEP;
}

extern "C" void kernel_launch(void* const* d_in, const int* in_sizes, int n_in,
                              void* d_out, int out_size, void* d_ws, size_t ws_size,
                              hipStream_t stream) {
    const float* x = (const float*)d_in[0];   // [1,1,64,128,128]
    const float* p = (const float*)d_in[1];   // [1,1,24,64,128]
    float* out  = (float*)d_out;              // [1,1,64,128,128]
    float* resT = (float*)d_ws;               // transposed filtered residual, NRAYS floats
    float* part = resT + NRAYS;               // 4 FP segments, 4*NRAYS floats

    dim3 fpg(NRAYS / 256, NSEG);
    fp_seg_kernel<<<fpg, 256, 0, stream>>>(x, part);
    ramp_kernel<<<NA * NV, NU, 0, stream>>>(part, p, resT);
    bp_gather10<<<128 * 32, 256, 0, stream>>>(resT, out);
}

// Round 13
// 507.874 us; speedup vs baseline: 1.5225x; 1.5225x over previous
//
#include <hip/hip_runtime.h>
#include <math.h>

// ---- geometry constants (match reference) ----
#define NA   24
#define NU   128
#define NV   64
#define NW   128   // volume W (x)
#define NH   128   // volume H (y)
#define ND   64    // volume D (z)
#define NS   128   // samples per ray
#define F_STEP 1.5625f            // 2*HS/S = 200/128
#define F_DL  (200.0f / 127.0f)   // linspace(156,356,128) spacing
#define F_L0  156.0f
#define INV_DL (127.0f / 200.0f)

#define NRAYS (NA * NV * NU)      // 196608
#define VOX   (NW * NH * ND)      // 1048576
#define NSEG  4

typedef float v2f __attribute__((ext_vector_type(2)));

// cos/sin(k*15 deg)
__device__ __constant__ float CSA[NA] = {
    1.0f,  0.96592582628906829f,  0.86602540378443865f,  0.70710678118654752f,
    0.5f,  0.25881904510252076f,  0.0f,                 -0.25881904510252076f,
   -0.5f, -0.70710678118654752f, -0.86602540378443865f, -0.96592582628906829f,
   -1.0f, -0.96592582628906829f, -0.86602540378443865f, -0.70710678118654752f,
   -0.5f, -0.25881904510252076f,  0.0f,                  0.25881904510252076f,
    0.5f,  0.70710678118654752f,  0.86602540378443865f,  0.96592582628906829f
};
__device__ __constant__ float SNA[NA] = {
    0.0f,  0.25881904510252076f,  0.5f,                  0.70710678118654752f,
    0.86602540378443865f,  0.96592582628906829f,  1.0f,  0.96592582628906829f,
    0.86602540378443865f,  0.70710678118654752f,  0.5f,  0.25881904510252076f,
    0.0f, -0.25881904510252076f, -0.5f,                 -0.70710678118654752f,
   -0.86602540378443865f, -0.96592582628906829f, -1.0f, -0.96592582628906829f,
   -0.86602540378443865f, -0.70710678118654752f, -0.5f, -0.25881904510252076f
};

// Per-ray geometry for FP.
__device__ __forceinline__ void ray_setup(int a, int v, int u,
                                          float& sx, float& sy,
                                          float& dx, float& dy, float& dz) {
    float ang = (float)((double)a * (15.0 * M_PI / 180.0));
    float c = cosf(ang), s = sinf(ang);
    float uu = (float)u - 63.5f;
    float vv = (float)v - 31.5f;
    float ux = 512.0f * c - uu * s;
    float uy = 512.0f * s + uu * c;
    float uz = vv;
    float invn = 1.0f / sqrtf(ux * ux + uy * uy + uz * uz);
    dx = ux * invn; dy = uy * invn; dz = uz * invn;
    sx = -256.0f * c; sy = -256.0f * s;
}

// ---------------- forward projection, 4 ell-segments ----------------
__global__ __launch_bounds__(256) void fp_seg_kernel(const float* __restrict__ vol,
                                                     float* __restrict__ part) {
    int r = blockIdx.x * blockDim.x + threadIdx.x;
    int seg = blockIdx.y;
    int u = r & (NU - 1);
    int v = (r >> 7) & (NV - 1);
    int a = r >> 13;

    float sx, sy, dx, dy, dz;
    ray_setup(a, v, u, sx, sy, dx, dy, dz);

    float rx = 1.0f / dx, ry = 1.0f / dy, rz = 1.0f / dz;
    float ex0 = (-64.55f - sx) * rx, ex1 = (64.55f - sx) * rx;
    float ey0 = (-64.55f - sy) * ry, ey1 = (64.55f - sy) * ry;
    float ez0 = (-32.55f) * rz,      ez1 = (32.55f) * rz;
    float llo = fmaxf(fmaxf(fminf(ex0, ex1), fminf(ey0, ey1)), fminf(ez0, ez1));
    float lhi = fminf(fminf(fmaxf(ex0, ex1), fmaxf(ey0, ey1)), fmaxf(ez0, ez1));
    int i_lo = max(seg * 32,      (int)ceilf((llo - F_L0) * INV_DL));
    int i_hi = min(seg * 32 + 31, (int)floorf((lhi - F_L0) * INV_DL));

    float acc = 0.0f;
    for (int i = i_lo; i <= i_hi; ++i) {
        float ell = F_L0 + F_DL * (float)i;
        float cx = sx + ell * dx + 63.5f;
        float cy = sy + ell * dy + 63.5f;
        float cz =      ell * dz + 31.5f;
        float fx = floorf(cx), fy = floorf(cy), fz = floorf(cz);
        int ix = (int)fx, iy = (int)fy, iz = (int)fz;
        float wx1 = cx - fx, wy1 = cy - fy, wz1 = cz - fz;
        float wx0 = 1.0f - wx1, wy0 = 1.0f - wy1, wz0 = 1.0f - wz1;
        bool bx0 = (unsigned)ix < NW,      bx1 = (unsigned)(ix + 1) < NW;
        bool by0 = (unsigned)iy < NH,      by1 = (unsigned)(iy + 1) < NH;
        bool bz0 = (unsigned)iz < ND,      bz1 = (unsigned)(iz + 1) < ND;
        long base = ((long)iz * NH + iy) * NW + ix;
        float v000 = (bz0 && by0 && bx0) ? vol[base]                 : 0.0f;
        float v001 = (bz0 && by0 && bx1) ? vol[base + 1]             : 0.0f;
        float v010 = (bz0 && by1 && bx0) ? vol[base + NW]            : 0.0f;
        float v011 = (bz0 && by1 && bx1) ? vol[base + NW + 1]        : 0.0f;
        float v100 = (bz1 && by0 && bx0) ? vol[base + NH * NW]       : 0.0f;
        float v101 = (bz1 && by0 && bx1) ? vol[base + NH * NW + 1]   : 0.0f;
        float v110 = (bz1 && by1 && bx0) ? vol[base + NH * NW + NW]  : 0.0f;
        float v111 = (bz1 && by1 && bx1) ? vol[base + NH * NW + NW + 1] : 0.0f;
        acc += wz0 * (wy0 * (wx0 * v000 + wx1 * v001) +
                      wy1 * (wx0 * v010 + wx1 * v011)) +
               wz1 * (wy0 * (wx0 * v100 + wx1 * v101) +
                      wy1 * (wx0 * v110 + wx1 * v111));
    }
    part[seg * NRAYS + r] = acc;
}

// ------- residual + cw + Ram-Lak; writes TRANSPOSED resT[a][u][v] -------
__global__ __launch_bounds__(NU) void ramp_kernel(const float* __restrict__ part,
                                                  const float* __restrict__ p,
                                                  float* __restrict__ resT) {
    __shared__ float row[NU];
    int rowid = blockIdx.x;          // a*NV + v
    int u = threadIdx.x;
    int e = rowid * NU + u;
    int a = rowid >> 6;
    int v = rowid & (NV - 1);
    float sino = (part[e] + part[NRAYS + e] + part[2 * NRAYS + e] + part[3 * NRAYS + e]) * F_STEP;
    double du = (double)u - 64.0;
    double dv = (double)v - 32.0;
    float cw = (float)(512.0 / sqrt(262144.0 + dv * dv + du * du));
    row[u] = (sino - p[e]) * cw;
    __syncthreads();
    float acc = 0.125f * row[u];
#pragma unroll
    for (int d = 1; d <= 63; d += 2) {
        float f = (float)(-0.5 / (M_PI * M_PI * (double)(d * d)));
        float lo = (u - d >= 0) ? row[u - d] : 0.0f;
        float hi = (u + d < NU) ? row[u + d] : 0.0f;
        acc += f * (lo + hi);
    }
    resT[(a << 13) + (u << 6) + v] = acc;   // [a][u][v]
}

// ---------------- back projection: dual-angle gather + prefetch, 3-bin splat ----------------
// R11 structure (angles j, j+12 interleaved; 2 chains) + one-ahead prefetch
// (load->use distance = 1 full iteration, covers ~200cyc L2 latency) + 3-bin
// register z-splat (fz spans < izb+2 provably -> bin izb+3 always zero).

#define SETUP_ANGLE(S, CC, SS)                                                   \
    const float c##S = (CC), sn##S = (SS);                                       \
    const float c512##S = 512.0f * c##S;                                         \
    const float s512##S = 512.0f * sn##S;                                        \
    const float rho##S = fmaf(x0, c##S, fmaf(y0, sn##S, 256.0f));                \
    const float Vx##S = x0 + 256.0f * c##S;                                      \
    const float Vy##S = y0 + 256.0f * sn##S;                                     \
    const float tvlo##S = (rho##S - ab1) * (1.0f / 512.0f);                      \
    const float yp##S = y0 * c##S - x0 * sn##S;                                  \
    const float rl##S = __builtin_amdgcn_rcpf(rho##S - ab1);                     \
    const float rh##S = __builtin_amdgcn_rcpf(rho##S + ab1);                     \
    const float A##S = yp##S - ab1, B##S = yp##S + ab1;                          \
    const float um##S = 512.0f * A##S * ((A##S >= 0.0f) ? rh##S : rl##S);        \
    const float uM##S = 512.0f * B##S * ((B##S >= 0.0f) ? rl##S : rh##S);        \
    const int u_lo##S = max(0,   (int)ceilf(um##S + 63.49f));                    \
    const int u_hi##S = min(127, (int)floorf(uM##S + 63.51f));                   \
    const int len##S = max(0, u_hi##S - u_lo##S + 1);                            \
    const float Zmin##S = fmaf(vvf, (vvf >= 0.0f) ? (tvlo##S - 1.0e-3f)          \
                                                  : (tvlo##S + 7.2e-3f), 31.5f); \
    const float izbf##S = floorf(Zmin##S);                                       \
    const int   izb##S  = (int)izbf##S;                                          \
    const v2f b0##S = {izbf##S, izbf##S};                                        \
    const float tDL##S = tvlo##S * INV_DL;                                       \
    const v2f mVx##S = {-Vx##S, -Vx##S}, mVy##S = {-Vy##S, -Vy##S};

#define BP_BODY2(S, RV, UU) do {                                                 \
    const float pu = fmaf(-(UU), sn##S, c512##S);                                \
    const float qu = fmaf((UU), c##S, s512##S);                                  \
    const float arg  = fmaf((UU), (UU), s2);                                     \
    const float invn = __builtin_amdgcn_rsqf(arg);                               \
    const float nn   = arg * invn;                                               \
    const float i0f  = ceilf(fmaf(tDL##S, nn, cK));                              \
    const float ell0 = fmaf(i0f, F_DL, F_L0);                                    \
    v2f tp; tp.x = ell0 * invn; tp.y = fmaf(F_DL, invn, tp.x);                   \
    const v2f pu2 = {pu, pu}, qu2 = {qu, qu};                                    \
    v2f wx = __builtin_elementwise_max(                                          \
        one2 - __builtin_elementwise_abs(__builtin_elementwise_fma(tp, pu2, mVx##S)), zero2); \
    v2f wy = __builtin_elementwise_max(                                          \
        one2 - __builtin_elementwise_abs(__builtin_elementwise_fma(tp, qu2, mVy##S)), zero2); \
    v2f val = wx * wy * (v2f){(RV), (RV)};                                       \
    const v2f fz2 = __builtin_elementwise_fma(tp, vv2, h31);                     \
    const v2f g = fz2 - b0##S;                                                   \
    AC0##S = __builtin_elementwise_fma(__builtin_elementwise_max(                \
             one2 - __builtin_elementwise_abs(g), zero2), val, AC0##S);          \
    AC1##S = __builtin_elementwise_fma(__builtin_elementwise_max(                \
             one2 - __builtin_elementwise_abs(g - one2), zero2), val, AC1##S);   \
    AC2##S = __builtin_elementwise_fma(__builtin_elementwise_max(                \
             one2 - __builtin_elementwise_abs(g - two2), zero2), val, AC2##S);   \
} while (0)

__global__ __launch_bounds__(256, 8) void bp_gather11(const float* __restrict__ resT,
                                                      float* __restrict__ out) {
    __shared__ float s_acc[4 * 64];       // per-wave z-accumulator columns

    const int tid  = threadIdx.x;
    const int lane = tid & 63;            // = v
    const int wv   = tid >> 6;            // wave 0..3
    const int y    = blockIdx.x & 127;    // y-major: adjacent blocks differ in y
    const int xq   = blockIdx.x >> 7;     // 0..31
    const int xi   = xq * 4 + wv;         // 4 consecutive x per block

    const float x0 = (float)xi - 63.5f;
    const float y0 = (float)y  - 63.5f;
    const float vvf = (float)lane - 31.5f;
    const float s2  = fmaf(vvf, vvf, 262144.0f);   // vv^2 + 512^2
    const v2f vv2   = {vvf, vvf};
    const v2f one2  = {1.0f, 1.0f}, zero2 = {0.0f, 0.0f};
    const v2f two2  = {2.0f, 2.0f};
    const v2f h31   = {31.5f, 31.5f};
    const float cK  = -(F_L0 * INV_DL) - 1.0e-3f;

    s_acc[tid] = 0.0f;

    for (int j = 0; j < NA / 2; ++j) {
        const float cj  = CSA[j];
        const float snj = SNA[j];
        const float ab1 = fabsf(cj) + fabsf(snj);

        SETUP_ANGLE(0, cj, snj);            // angle j
        SETUP_ANGLE(1, -cj, -snj);          // angle j+12 (opposite)

        const int trips = max(len0, len1);
        if (trips == 0) continue;
        const int us0 = max(0, min(u_lo0, 128 - trips));
        const int us1 = max(0, min(u_lo1, 128 - trips));

        v2f AC00 = zero2, AC10 = zero2, AC20 = zero2;
        v2f AC01 = zero2, AC11 = zero2, AC21 = zero2;

        const float* ru0 = resT + (j << 13)        + (us0 << 6) + lane;
        const float* ru1 = resT + ((j + 12) << 13) + (us1 << 6) + lane;
        float uu0 = (float)us0 - 63.5f;
        float uu1 = (float)us1 - 63.5f;

        float rv0 = ru0[0], rv1 = ru1[0];
#pragma unroll 1
        for (int k = 0; k < trips; ++k) {
            ru0 += 64; ru1 += 64;
            const float nv0 = ru0[0];      // one-ahead prefetch; the final read
            const float nv1 = ru1[0];      // (1 col past window) stays in ws
            BP_BODY2(0, rv0, uu0);
            BP_BODY2(1, rv1, uu1);
            rv0 = nv0; rv1 = nv1;
            uu0 += 1.0f; uu1 += 1.0f;
        }

        float* accw = s_acc + (wv << 6);      // wave-private column
        atomicAdd(&accw[izb0],     AC00.x + AC00.y);
        atomicAdd(&accw[izb0 + 1], AC10.x + AC10.y);
        atomicAdd(&accw[izb0 + 2], AC20.x + AC20.y);
        atomicAdd(&accw[izb1],     AC01.x + AC01.y);
        atomicAdd(&accw[izb1 + 1], AC11.x + AC11.y);
        atomicAdd(&accw[izb1 + 2], AC21.x + AC21.y);
    }
    __syncthreads();

    // writeout: 4 consecutive x per 4 lanes -> 16B chunks
    const int z  = tid >> 2;
    const int w4 = tid & 3;
    out[(z << 14) + (y << 7) + xq * 4 + w4] = s_acc[(w4 << 6) + z] * F_STEP;
}

extern "C" void kernel_launch(void* const* d_in, const int* in_sizes, int n_in,
                              void* d_out, int out_size, void* d_ws, size_t ws_size,
                              hipStream_t stream) {
    const float* x = (const float*)d_in[0];   // [1,1,64,128,128]
    const float* p = (const float*)d_in[1];   // [1,1,24,64,128]
    float* out  = (float*)d_out;              // [1,1,64,128,128]
    float* resT = (float*)d_ws;               // transposed filtered residual, NRAYS floats
    float* part = resT + NRAYS;               // 4 FP segments, 4*NRAYS floats

    dim3 fpg(NRAYS / 256, NSEG);
    fp_seg_kernel<<<fpg, 256, 0, stream>>>(x, part);
    ramp_kernel<<<NA * NV, NU, 0, stream>>>(part, p, resT);
    bp_gather11<<<128 * 32, 256, 0, stream>>>(resT, out);
}